// Round 1
// baseline (209.314 us; speedup 1.0000x reference)
//
#include <hip/hip_runtime.h>

// Problem constants: B=4, C=256, H=W=64, KS=3, N=9
#define HW    4096
#define J_TOT 16384   // B*H*W
#define K_TOT 2304    // 9*256
#define C_CH  256

typedef unsigned short u16;
typedef unsigned int   u32;
typedef __attribute__((ext_vector_type(8))) short short8;   // 8 bf16 (4 VGPRs), MFMA A/B frag
typedef __attribute__((ext_vector_type(4))) float f32x4;    // MFMA C/D frag
typedef __attribute__((ext_vector_type(4))) unsigned short us4;

__device__ __forceinline__ float b2f(u16 u) { return __uint_as_float(((u32)u) << 16); }
__device__ __forceinline__ u16 f2b(float x) {             // RNE f32->bf16
  u32 u = __float_as_uint(x);
  u += 0x7FFFu + ((u >> 16) & 1u);
  return (u16)(u >> 16);
}

// async global->LDS, 16B per lane; lds dst must be wave-uniform base (+lane*16 implicit)
__device__ __forceinline__ void gload_lds16(const u16* g, u16* l) {
  __builtin_amdgcn_global_load_lds(
      (__attribute__((address_space(1))) void*)(void*)g,
      (__attribute__((address_space(3))) void*)(void*)l, 16, 0, 0);
}

// ---------------------------------------------------------------------------
// Kernel 0: dtype detection. bf16 data: even halfwords are real bf16s
// (exponent field in normal range ~always). f32 data: even halfwords are low
// mantissa bits (uniform -> ~16% in range). Writes flag: 1 = bf16, 0 = f32.
// ---------------------------------------------------------------------------
__global__ void k_detect(const u16* __restrict__ f, int* __restrict__ flag) {
  __shared__ int sh[256];
  int t = threadIdx.x;
  int hits = 0;
  for (int i = t; i < 2048; i += 256) {
    u16 u = f[2 * i];
    int e = (u >> 7) & 0xFF;
    hits += (e >= 100 && e <= 141) ? 1 : 0;
  }
  sh[t] = hits;
  __syncthreads();
  if (t == 0) {
    int s = 0;
    for (int i = 0; i < 256; i++) s += sh[i];
    flag[0] = (s > 1024) ? 1 : 0;
  }
}

// ---------------------------------------------------------------------------
// Kernel 1: feature (b,c,h,w) -> channels-last fp32 ftr[b][hw][c]
// 32x32 LDS tiled transpose per batch; coalesced both directions.
// ---------------------------------------------------------------------------
__global__ void k_transpose(const void* __restrict__ featv, float* __restrict__ ftr,
                            const int* __restrict__ flag) {
  __shared__ float tile[32][33];
  int isbf = *flag;
  int b = blockIdx.z;
  int hw0 = blockIdx.x << 5;
  int c0 = blockIdx.y << 5;
  int tx = threadIdx.x;  // 0..31 (hw on load, c on store)
  int ty = threadIdx.y;  // 0..7
  if (isbf) {
    const u16* f = (const u16*)featv;
#pragma unroll
    for (int i = 0; i < 4; i++) {
      int c = c0 + ty + i * 8;
      tile[ty + i * 8][tx] = b2f(f[(((size_t)(b * C_CH + c)) << 12) + hw0 + tx]);
    }
  } else {
    const float* f = (const float*)featv;
#pragma unroll
    for (int i = 0; i < 4; i++) {
      int c = c0 + ty + i * 8;
      tile[ty + i * 8][tx] = f[(((size_t)(b * C_CH + c)) << 12) + hw0 + tx];
    }
  }
  __syncthreads();
#pragma unroll
  for (int i = 0; i < 4; i++) {
    int hw = hw0 + ty + i * 8;
    ftr[(((size_t)(b * HW + hw)) << 8) + c0 + tx] = tile[tx][ty + i * 8];
  }
}

// ---------------------------------------------------------------------------
// Kernel 2: weight (o,c,3,3) -> Wr[o][k] bf16 with k = n*256 + c, n = i*3+j
// ---------------------------------------------------------------------------
__global__ void k_wconv(const void* __restrict__ wv, u16* __restrict__ Wr,
                        const int* __restrict__ flag) {
  int isbf = *flag;
  int idx = blockIdx.x * 256 + threadIdx.x;      // = o*2304 + n*256 + c
  if (idx >= C_CH * K_TOT) return;
  int c = idx & 255;
  int n = (idx >> 8) % 9;
  int o = idx / K_TOT;
  int src = (o * 256 + c) * 9 + n;
  if (isbf) Wr[idx] = ((const u16*)wv)[src];
  else      Wr[idx] = f2b(((const float*)wv)[src]);
}

// ---------------------------------------------------------------------------
// Kernel 3: bilinear gather -> Xt[j][k] bf16 (j = b*4096+hw, k = n*256+c).
// Block = 64 pixels x 256 threads. Phase 1: per (pixel,n) compute 4 corner
// base indices + 4 weights exactly like the reference (invalid/pad corner ->
// g=0, idx=0). Phase 2: thread (p,cq) produces 4 c's per iter via float4
// reads of channels-last ftr, writes ushort4 (8B) chunks of the K-contiguous
// Xt row.
// ---------------------------------------------------------------------------
__global__ __launch_bounds__(256) void k_gather(const void* __restrict__ offv,
                                                const float* __restrict__ ftr,
                                                u16* __restrict__ Xt,
                                                const int* __restrict__ flag) {
  __shared__ float gs[9][4][64];
  __shared__ int   isx[9][4][64];
  int isbf = *flag;
  int j0 = blockIdx.x << 6;
  int b = j0 >> 12;
  int hw0 = j0 & (HW - 1);

  for (int task = threadIdx.x; task < 576; task += 256) {
    int p = task & 63, n = task >> 6;
    int hw = hw0 + p;
    int h = hw >> 6, w = hw & 63;
    size_t obi = (((size_t)(b * 18 + n)) << 12) + hw;
    float ox, oy;
    if (isbf) {
      const u16* po = (const u16*)offv;
      ox = b2f(po[obi]);
      oy = b2f(po[obi + (9u << 12)]);
    } else {
      const float* po = (const float*)offv;
      ox = po[obi];
      oy = po[obi + (9u << 12)];
    }
    int ki = n / 3, kj = n % 3;
    // p = p0 + p_n + off: p0_x = h+1, pn_x = ki-1  => h + ki (+off)
    float px = (float)(h + ki) + ox;
    float py = (float)(w + kj) + oy;
    float fx = floorf(px), fy = floorf(py);
    float qltx = fminf(fmaxf(fx, 0.f), 65.f);
    float qlty = fminf(fmaxf(fy, 0.f), 65.f);
    float qrbx = fminf(fmaxf(fx + 1.f, 0.f), 65.f);
    float qrby = fminf(fmaxf(fy + 1.f, 0.f), 65.f);
    float pcx = fminf(fmaxf(px, 0.f), 65.f);
    float pcy = fminf(fmaxf(py, 0.f), 65.f);
    float dltx = 1.f + (qltx - pcx);
    float drbx = 1.f - (qrbx - pcx);
    float dlty = 1.f + (qlty - pcy);
    float drby = 1.f - (qrby - pcy);
    float g0 = dltx * dlty;   // (q_lt_x, q_lt_y)
    float g1 = drbx * drby;   // (q_rb_x, q_rb_y)
    float g2 = dltx * drby;   // (q_lt_x, q_rb_y)
    float g3 = drbx * dlty;   // (q_rb_x, q_lt_y)
    int x0 = (int)qltx, y0 = (int)qlty, x1 = (int)qrbx, y1 = (int)qrby;
    int v0 = (x0 >= 1 && x0 <= 64 && y0 >= 1 && y0 <= 64);
    int v1 = (x1 >= 1 && x1 <= 64 && y1 >= 1 && y1 <= 64);
    int v2 = (x0 >= 1 && x0 <= 64 && y1 >= 1 && y1 <= 64);
    int v3 = (x1 >= 1 && x1 <= 64 && y0 >= 1 && y0 <= 64);
    int base = b << 12;
    isx[n][0][p] = v0 ? ((base + ((x0 - 1) << 6) + (y0 - 1)) << 8) : 0;
    isx[n][1][p] = v1 ? ((base + ((x1 - 1) << 6) + (y1 - 1)) << 8) : 0;
    isx[n][2][p] = v2 ? ((base + ((x0 - 1) << 6) + (y1 - 1)) << 8) : 0;
    isx[n][3][p] = v3 ? ((base + ((x1 - 1) << 6) + (y0 - 1)) << 8) : 0;
    gs[n][0][p] = v0 ? g0 : 0.f;
    gs[n][1][p] = v1 ? g1 : 0.f;
    gs[n][2][p] = v2 ? g2 : 0.f;
    gs[n][3][p] = v3 ? g3 : 0.f;
  }
  __syncthreads();

  int p = threadIdx.x >> 2, cq = threadIdx.x & 3;
  size_t rowb = (size_t)(j0 + p) * K_TOT;
  for (int n = 0; n < 9; n++) {
    float g0 = gs[n][0][p], g1 = gs[n][1][p], g2 = gs[n][2][p], g3 = gs[n][3][p];
    const float* f0 = ftr + isx[n][0][p];
    const float* f1 = ftr + isx[n][1][p];
    const float* f2 = ftr + isx[n][2][p];
    const float* f3 = ftr + isx[n][3][p];
    u16* dst = Xt + rowb + n * 256;
#pragma unroll 4
    for (int cb = 0; cb < 16; cb++) {
      int c = cb * 16 + cq * 4;
      float4 a0 = *(const float4*)(f0 + c);
      float4 a1 = *(const float4*)(f1 + c);
      float4 a2 = *(const float4*)(f2 + c);
      float4 a3 = *(const float4*)(f3 + c);
      float rx = g0 * a0.x + g1 * a1.x + g2 * a2.x + g3 * a3.x;
      float ry = g0 * a0.y + g1 * a1.y + g2 * a2.y + g3 * a3.y;
      float rz = g0 * a0.z + g1 * a1.z + g2 * a2.z + g3 * a3.z;
      float rw = g0 * a0.w + g1 * a1.w + g2 * a2.w + g3 * a3.w;
      us4 o;
      o.x = f2b(rx); o.y = f2b(ry); o.z = f2b(rz); o.w = f2b(rw);
      *(us4*)(dst + c) = o;
    }
  }
}

// ---------------------------------------------------------------------------
// Kernel 4: GEMM  out[o][j] = sum_k Wr[o][k]*Xt[j][k], fused epilogue
// relu(relu(acc) + feature). m97 structure: 128x128 tile, BK=32, 4 waves 2x2
// (64x64 each, 4x4 frags of 16x16x32), global_load_lds width-16 staging.
// ---------------------------------------------------------------------------
__global__ __launch_bounds__(256) void k_gemm(const u16* __restrict__ Wr,
                                              const u16* __restrict__ Xt,
                                              const void* __restrict__ featv,
                                              void* __restrict__ outv,
                                              const int* __restrict__ flag) {
  __shared__ u16 As[128 * 32];   // [o_row][k] 8KB
  __shared__ u16 Bs[128 * 32];   // [j_row][k] 8KB
  int isbf = *flag;
  int jb = blockIdx.x << 7;
  int ob = blockIdx.y << 7;
  int t = threadIdx.x;
  int wave = t >> 6, lane = t & 63;
  int wm = wave >> 1, wn = wave & 1;

  f32x4 acc[4][4];
  f32x4 zero = {0.f, 0.f, 0.f, 0.f};
#pragma unroll
  for (int i = 0; i < 4; i++)
#pragma unroll
    for (int j = 0; j < 4; j++) acc[i][j] = zero;

  // staging: 8 chunks of 1KB per tile; wave q stages chunks 2q, 2q+1
  int q0 = wave * 2, q1 = q0 + 1;
  int fi0 = q0 * 64 + lane, fi1 = q1 * 64 + lane;   // flat 16B-slot index
  const u16* ag0 = Wr + (size_t)(ob + (fi0 >> 2)) * K_TOT + (fi0 & 3) * 8;
  const u16* ag1 = Wr + (size_t)(ob + (fi1 >> 2)) * K_TOT + (fi1 & 3) * 8;
  const u16* bg0 = Xt + (size_t)(jb + (fi0 >> 2)) * K_TOT + (fi0 & 3) * 8;
  const u16* bg1 = Xt + (size_t)(jb + (fi1 >> 2)) * K_TOT + (fi1 & 3) * 8;
  u16* al0 = &As[q0 * 512];
  u16* al1 = &As[q1 * 512];
  u16* bl0 = &Bs[q0 * 512];
  u16* bl1 = &Bs[q1 * 512];

  int lr = lane & 15, lk = lane >> 4;
  const u16* ar = &As[(wm * 64 + lr) * 32 + lk * 8];
  const u16* br = &Bs[(wn * 64 + lr) * 32 + lk * 8];

  for (int k0 = 0; k0 < K_TOT; k0 += 32) {
    gload_lds16(ag0 + k0, al0);
    gload_lds16(ag1 + k0, al1);
    gload_lds16(bg0 + k0, bl0);
    gload_lds16(bg1 + k0, bl1);
    __syncthreads();
    short8 a[4], bf[4];
#pragma unroll
    for (int mi = 0; mi < 4; mi++) a[mi] = *(const short8*)(ar + mi * 16 * 32);
#pragma unroll
    for (int ni = 0; ni < 4; ni++) bf[ni] = *(const short8*)(br + ni * 16 * 32);
#pragma unroll
    for (int mi = 0; mi < 4; mi++)
#pragma unroll
      for (int ni = 0; ni < 4; ni++)
        acc[mi][ni] = __builtin_amdgcn_mfma_f32_16x16x32_bf16(a[mi], bf[ni], acc[mi][ni], 0, 0, 0);
    __syncthreads();
  }

  // epilogue: D mapping col = lane&15 (j), row = (lane>>4)*4 + r (o)
  int lq = lane >> 4;
#pragma unroll
  for (int mi = 0; mi < 4; mi++) {
#pragma unroll
    for (int ni = 0; ni < 4; ni++) {
      int j = jb + wn * 64 + ni * 16 + lr;
      int bb = j >> 12, hw = j & (HW - 1);
      int o0 = ob + wm * 64 + mi * 16 + lq * 4;
#pragma unroll
      for (int r = 0; r < 4; r++) {
        size_t oi = (((size_t)(bb * C_CH + o0 + r)) << 12) + hw;
        float v = acc[mi][ni][r];
        v = fmaxf(v, 0.f);
        float ft = isbf ? b2f(((const u16*)featv)[oi]) : ((const float*)featv)[oi];
        v = fmaxf(v + ft, 0.f);
        if (isbf) ((u16*)outv)[oi] = f2b(v);
        else      ((float*)outv)[oi] = v;
      }
    }
  }
}

extern "C" void kernel_launch(void* const* d_in, const int* in_sizes, int n_in,
                              void* d_out, int out_size, void* d_ws, size_t ws_size,
                              hipStream_t stream) {
  const void* feat = d_in[0];
  const void* offs = d_in[1];
  const void* wght = d_in[2];

  // workspace layout (256B-aligned sections)
  const size_t off_flag = 0;
  const size_t off_ftr  = 256;                          // fp32 channels-last feature, 16 MB
  const size_t off_wr   = off_ftr + (size_t)16777216;   // bf16 Wr, 1.125 MB
  const size_t off_xt   = off_wr + (size_t)1179648;     // bf16 Xt, 72 MB
  const size_t need     = off_xt + (size_t)75497472;
  if (ws_size < need) return;  // insufficient scratch; cannot run

  char* ws = (char*)d_ws;
  int*   flag = (int*)(ws + off_flag);
  float* ftr  = (float*)(ws + off_ftr);
  u16*   Wr   = (u16*)(ws + off_wr);
  u16*   Xt   = (u16*)(ws + off_xt);

  k_detect<<<1, 256, 0, stream>>>((const u16*)feat, flag);
  k_transpose<<<dim3(128, 8, 4), dim3(32, 8), 0, stream>>>(feat, ftr, flag);
  k_wconv<<<K_TOT, 256, 0, stream>>>(wght, Wr, flag);
  k_gather<<<J_TOT / 64, 256, 0, stream>>>(offs, ftr, Xt, flag);
  k_gemm<<<dim3(J_TOT / 128, 2), 256, 0, stream>>>(Wr, Xt, feat, d_out, flag);
}

// Round 2
// 142.325 us; speedup vs baseline: 1.4707x; 1.4707x over previous
//
#include <hip/hip_runtime.h>

// Problem constants: B=4, C=256, H=W=64, KS=3, N=9
#define HW    4096
#define J_TOT 16384   // B*H*W
#define K_TOT 2304    // 9*256
#define C_CH  256

typedef unsigned short u16;
typedef unsigned int   u32;
typedef __attribute__((ext_vector_type(8))) short short8;   // 8 bf16 (4 VGPRs), MFMA A/B frag
typedef __attribute__((ext_vector_type(4))) float f32x4;    // MFMA C/D frag
typedef __attribute__((ext_vector_type(8))) unsigned short us8;

__device__ __forceinline__ float b2f(u16 u) { return __uint_as_float(((u32)u) << 16); }
__device__ __forceinline__ u16 f2b(float x) {             // RNE f32->bf16
  u32 u = __float_as_uint(x);
  u += 0x7FFFu + ((u >> 16) & 1u);
  return (u16)(u >> 16);
}

// async global->LDS, 16B per lane; lds dst must be wave-uniform base (+lane*16 implicit)
__device__ __forceinline__ void gload_lds16(const u16* g, u16* l) {
  __builtin_amdgcn_global_load_lds(
      (__attribute__((address_space(1))) void*)(void*)g,
      (__attribute__((address_space(3))) void*)(void*)l, 16, 0, 0);
}

// ---------------------------------------------------------------------------
// Kernel 0: dtype detection (1 = bf16 inputs, 0 = f32 inputs).
// ---------------------------------------------------------------------------
__global__ void k_detect(const u16* __restrict__ f, int* __restrict__ flag) {
  __shared__ int sh[256];
  int t = threadIdx.x;
  int hits = 0;
  for (int i = t; i < 2048; i += 256) {
    u16 u = f[2 * i];
    int e = (u >> 7) & 0xFF;
    hits += (e >= 100 && e <= 141) ? 1 : 0;
  }
  sh[t] = hits;
  __syncthreads();
  if (t == 0) {
    int s = 0;
    for (int i = 0; i < 256; i++) s += sh[i];
    flag[0] = (s > 1024) ? 1 : 0;
  }
}

// ---------------------------------------------------------------------------
// Kernel 1: feature (b,c,h,w) -> channels-last bf16 ftr[b][hw][c]
// ---------------------------------------------------------------------------
__global__ void k_transpose(const void* __restrict__ featv, u16* __restrict__ ftr,
                            const int* __restrict__ flag) {
  __shared__ u16 tile[32][33];
  int isbf = *flag;
  int b = blockIdx.z;
  int hw0 = blockIdx.x << 5;
  int c0 = blockIdx.y << 5;
  int tx = threadIdx.x;  // 0..31 (hw on load, c on store)
  int ty = threadIdx.y;  // 0..7
  if (isbf) {
    const u16* f = (const u16*)featv;
#pragma unroll
    for (int i = 0; i < 4; i++) {
      int c = c0 + ty + i * 8;
      tile[ty + i * 8][tx] = f[(((size_t)(b * C_CH + c)) << 12) + hw0 + tx];
    }
  } else {
    const float* f = (const float*)featv;
#pragma unroll
    for (int i = 0; i < 4; i++) {
      int c = c0 + ty + i * 8;
      tile[ty + i * 8][tx] = f2b(f[(((size_t)(b * C_CH + c)) << 12) + hw0 + tx]);
    }
  }
  __syncthreads();
#pragma unroll
  for (int i = 0; i < 4; i++) {
    int hw = hw0 + ty + i * 8;
    ftr[(((size_t)(b * HW + hw)) << 8) + c0 + tx] = tile[tx][ty + i * 8];
  }
}

// ---------------------------------------------------------------------------
// Kernel 2: weight (o,c,3,3) -> Wr[o][k] bf16 with k = n*256 + c, n = i*3+j
// ---------------------------------------------------------------------------
__global__ void k_wconv(const void* __restrict__ wv, u16* __restrict__ Wr,
                        const int* __restrict__ flag) {
  int isbf = *flag;
  int idx = blockIdx.x * 256 + threadIdx.x;      // = o*2304 + n*256 + c
  if (idx >= C_CH * K_TOT) return;
  int c = idx & 255;
  int n = (idx >> 8) % 9;
  int o = idx / K_TOT;
  int src = (o * 256 + c) * 9 + n;
  if (isbf) Wr[idx] = ((const u16*)wv)[src];
  else      Wr[idx] = f2b(((const float*)wv)[src]);
}

// ---------------------------------------------------------------------------
// Kernel 3: bilinear gather -> Xt[j][k] bf16 (j = b*4096+hw, k = n*256+c).
// 16 pixels per block (1024 blocks = 4 blocks/CU). Phase 1: per (pixel,n)
// corner indices + weights (identical math to round-1, verified). Phase 2:
// thread (p,cq) handles channels cq*8..+8 and 128+cq*8..+8 -> each 16-lane
// group's us8 loads cover a dense 256B segment of a bf16 corner row.
// ---------------------------------------------------------------------------
__global__ __launch_bounds__(256) void k_gather(const void* __restrict__ offv,
                                                const u16* __restrict__ ftr,
                                                u16* __restrict__ Xt,
                                                const int* __restrict__ flag) {
  __shared__ float gs[9][4][16];
  __shared__ int   isx[9][4][16];
  int isbf = *flag;
  int j0 = blockIdx.x << 4;
  int b = j0 >> 12;
  int hw0 = j0 & (HW - 1);
  int t = threadIdx.x;

  if (t < 144) {
    int p = t & 15, n = t >> 4;
    int hw = hw0 + p;
    int h = hw >> 6, w = hw & 63;
    size_t obi = (((size_t)(b * 18 + n)) << 12) + hw;
    float ox, oy;
    if (isbf) {
      const u16* po = (const u16*)offv;
      ox = b2f(po[obi]);
      oy = b2f(po[obi + (9u << 12)]);
    } else {
      const float* po = (const float*)offv;
      ox = po[obi];
      oy = po[obi + (9u << 12)];
    }
    int ki = n / 3, kj = n % 3;
    float px = (float)(h + ki) + ox;
    float py = (float)(w + kj) + oy;
    float fx = floorf(px), fy = floorf(py);
    float qltx = fminf(fmaxf(fx, 0.f), 65.f);
    float qlty = fminf(fmaxf(fy, 0.f), 65.f);
    float qrbx = fminf(fmaxf(fx + 1.f, 0.f), 65.f);
    float qrby = fminf(fmaxf(fy + 1.f, 0.f), 65.f);
    float pcx = fminf(fmaxf(px, 0.f), 65.f);
    float pcy = fminf(fmaxf(py, 0.f), 65.f);
    float dltx = 1.f + (qltx - pcx);
    float drbx = 1.f - (qrbx - pcx);
    float dlty = 1.f + (qlty - pcy);
    float drby = 1.f - (qrby - pcy);
    float g0 = dltx * dlty;   // (q_lt_x, q_lt_y)
    float g1 = drbx * drby;   // (q_rb_x, q_rb_y)
    float g2 = dltx * drby;   // (q_lt_x, q_rb_y)
    float g3 = drbx * dlty;   // (q_rb_x, q_lt_y)
    int x0 = (int)qltx, y0 = (int)qlty, x1 = (int)qrbx, y1 = (int)qrby;
    int v0 = (x0 >= 1 && x0 <= 64 && y0 >= 1 && y0 <= 64);
    int v1 = (x1 >= 1 && x1 <= 64 && y1 >= 1 && y1 <= 64);
    int v2 = (x0 >= 1 && x0 <= 64 && y1 >= 1 && y1 <= 64);
    int v3 = (x1 >= 1 && x1 <= 64 && y0 >= 1 && y0 <= 64);
    int base = b << 12;
    isx[n][0][p] = v0 ? ((base + ((x0 - 1) << 6) + (y0 - 1)) << 8) : 0;
    isx[n][1][p] = v1 ? ((base + ((x1 - 1) << 6) + (y1 - 1)) << 8) : 0;
    isx[n][2][p] = v2 ? ((base + ((x0 - 1) << 6) + (y1 - 1)) << 8) : 0;
    isx[n][3][p] = v3 ? ((base + ((x1 - 1) << 6) + (y0 - 1)) << 8) : 0;
    gs[n][0][p] = v0 ? g0 : 0.f;
    gs[n][1][p] = v1 ? g1 : 0.f;
    gs[n][2][p] = v2 ? g2 : 0.f;
    gs[n][3][p] = v3 ? g3 : 0.f;
  }
  __syncthreads();

  int p = t >> 4, cq = t & 15;
  size_t rowb = (size_t)(j0 + p) * K_TOT;
  int cA = cq * 8, cB = 128 + cq * 8;
  for (int n = 0; n < 9; n++) {
    float g0 = gs[n][0][p], g1 = gs[n][1][p], g2 = gs[n][2][p], g3 = gs[n][3][p];
    const u16* f0 = ftr + isx[n][0][p];
    const u16* f1 = ftr + isx[n][1][p];
    const u16* f2 = ftr + isx[n][2][p];
    const u16* f3 = ftr + isx[n][3][p];
    u16* dst = Xt + rowb + n * 256;
#pragma unroll
    for (int half = 0; half < 2; half++) {
      int c = half ? cB : cA;
      us8 r0 = *(const us8*)(f0 + c);
      us8 r1 = *(const us8*)(f1 + c);
      us8 r2 = *(const us8*)(f2 + c);
      us8 r3 = *(const us8*)(f3 + c);
      us8 ov;
#pragma unroll
      for (int i = 0; i < 8; i++) {
        float v = g0 * b2f(r0[i]) + g1 * b2f(r1[i]) + g2 * b2f(r2[i]) + g3 * b2f(r3[i]);
        ov[i] = f2b(v);
      }
      *(us8*)(dst + c) = ov;
    }
  }
}

// ---------------------------------------------------------------------------
// Kernel 4: GEMM  out[o][j] = sum_k Wr[o][k]*Xt[j][k], fused epilogue
// relu(relu(acc) + feature). Tile 128j x 64o, 4 waves (2j x 2o), wave tile
// 64j x 32o (4x2 frags of 16x16x32). Grid (128,4) = 512 blocks = 2 blocks/CU
// = 8 waves/CU. LDS 12KB, XOR-swizzled (col ^= (row>>1)&3) so fragment
// ds_read_b128s are 2-way (free) instead of 8-way.
// ---------------------------------------------------------------------------
__global__ __launch_bounds__(256) void k_gemm(const u16* __restrict__ Wr,
                                              const u16* __restrict__ Xt,
                                              const void* __restrict__ featv,
                                              void* __restrict__ outv,
                                              const int* __restrict__ flag) {
  __shared__ u16 Bs[128 * 32];   // [j_row][k] 8KB
  __shared__ u16 As[64 * 32];    // [o_row][k] 4KB
  int isbf = *flag;
  int jb = blockIdx.x << 7;
  int ob0 = blockIdx.y << 6;
  int t = threadIdx.x;
  int wave = t >> 6, lane = t & 63;
  int wj = wave >> 1, wo = wave & 1;
  int lr = lane & 15, lk = lane >> 4;

  f32x4 acc[2][4];   // [oi][ji]
  f32x4 zero = {0.f, 0.f, 0.f, 0.f};
#pragma unroll
  for (int i = 0; i < 2; i++)
#pragma unroll
    for (int j = 0; j < 4; j++) acc[i][j] = zero;

  // staging: B slots 0..511 (wave w: w*64+lane and 256+w*64+lane),
  //          A slots 0..255 (wave w: w*64+lane). Swizzle source column.
  int s0 = wave * 64 + lane;
  int s1 = 256 + s0;
  int r0 = s0 >> 2, cg0 = (s0 & 3) ^ ((r0 >> 1) & 3);
  int r1 = s1 >> 2, cg1 = (s1 & 3) ^ ((r1 >> 1) & 3);
  const u16* bg0 = Xt + (size_t)(jb + r0) * K_TOT + cg0 * 8;
  const u16* bg1 = Xt + (size_t)(jb + r1) * K_TOT + cg1 * 8;
  const u16* ag  = Wr + (size_t)(ob0 + r0) * K_TOT + cg0 * 8;
  u16* bl0 = &Bs[wave * 512];
  u16* bl1 = &Bs[2048 + wave * 512];
  u16* al  = &As[wave * 512];

  int swz = (lr >> 1) & 3;
  const u16* ar = &As[(wo * 32 + lr) * 32 + (lk ^ swz) * 8];
  const u16* br = &Bs[(wj * 64 + lr) * 32 + (lk ^ swz) * 8];

  for (int k0 = 0; k0 < K_TOT; k0 += 32) {
    gload_lds16(bg0 + k0, bl0);
    gload_lds16(bg1 + k0, bl1);
    gload_lds16(ag + k0, al);
    __syncthreads();
    short8 a[2], bb[4];
#pragma unroll
    for (int oi = 0; oi < 2; oi++) a[oi] = *(const short8*)(ar + oi * 512);
#pragma unroll
    for (int ji = 0; ji < 4; ji++) bb[ji] = *(const short8*)(br + ji * 512);
#pragma unroll
    for (int oi = 0; oi < 2; oi++)
#pragma unroll
      for (int ji = 0; ji < 4; ji++)
        acc[oi][ji] = __builtin_amdgcn_mfma_f32_16x16x32_bf16(a[oi], bb[ji], acc[oi][ji], 0, 0, 0);
    __syncthreads();
  }

  // epilogue: D mapping col = lane&15 (j), row = (lane>>4)*4 + r (o)
  int lq = lane >> 4;
#pragma unroll
  for (int oi = 0; oi < 2; oi++) {
#pragma unroll
    for (int ji = 0; ji < 4; ji++) {
      int j = jb + wj * 64 + ji * 16 + lr;
      int bb_ = j >> 12, hw = j & (HW - 1);
      int o0 = ob0 + wo * 32 + oi * 16 + lq * 4;
#pragma unroll
      for (int r = 0; r < 4; r++) {
        size_t oidx = (((size_t)(bb_ * C_CH + o0 + r)) << 12) + hw;
        float v = acc[oi][ji][r];
        v = fmaxf(v, 0.f);
        float ft = isbf ? b2f(((const u16*)featv)[oidx]) : ((const float*)featv)[oidx];
        v = fmaxf(v + ft, 0.f);
        if (isbf) ((u16*)outv)[oidx] = f2b(v);
        else      ((float*)outv)[oidx] = v;
      }
    }
  }
}

extern "C" void kernel_launch(void* const* d_in, const int* in_sizes, int n_in,
                              void* d_out, int out_size, void* d_ws, size_t ws_size,
                              hipStream_t stream) {
  const void* feat = d_in[0];
  const void* offs = d_in[1];
  const void* wght = d_in[2];

  // workspace layout (256B-aligned sections), total ~85.1 MB
  const size_t off_flag = 0;
  const size_t off_wr   = 256;                          // bf16 Wr, 1.125 MB
  const size_t off_ftr  = off_wr + (size_t)1179648;     // bf16 channels-last feature, 8 MB
  const size_t off_xt   = off_ftr + (size_t)8388608;    // bf16 Xt, 72 MB
  const size_t need     = off_xt + (size_t)75497472;
  if (ws_size < need) return;  // insufficient scratch; cannot run

  char* ws = (char*)d_ws;
  int* flag = (int*)(ws + off_flag);
  u16* Wr   = (u16*)(ws + off_wr);
  u16* ftr  = (u16*)(ws + off_ftr);
  u16* Xt   = (u16*)(ws + off_xt);

  k_detect<<<1, 256, 0, stream>>>((const u16*)feat, flag);
  k_transpose<<<dim3(128, 8, 4), dim3(32, 8), 0, stream>>>(feat, ftr, flag);
  k_wconv<<<K_TOT, 256, 0, stream>>>(wght, Wr, flag);
  k_gather<<<J_TOT / 16, 256, 0, stream>>>(offs, ftr, Xt, flag);
  k_gemm<<<dim3(J_TOT / 128, 4), 256, 0, stream>>>(Wr, Xt, feat, d_out, flag);
}